// Round 1
// baseline (192.040 us; speedup 1.0000x reference)
//
#include <hip/hip_runtime.h>

// MHA forward: S=2048, B=4, E=512, H=8, D=64.
// Pipeline: qkv_kernel (3x GEMM 8192x512x512, bf16 MFMA) -> attn_kernel
// (flash attention, 64-q-row tiles, KV blocks of 64) -> oproj_kernel (GEMM).
// All intermediates bf16 in d_ws; accumulation fp32 throughout.

#define L2E 1.44269504088896340736f

typedef __attribute__((ext_vector_type(8))) __bf16 bf16x8;
typedef __attribute__((ext_vector_type(4))) float f32x4;

static __device__ __forceinline__ unsigned short f2bf(float f) {
    union { float f; unsigned u; } v; v.f = f;
    unsigned u = v.u + 0x7fffu + ((v.u >> 16) & 1u);
    return (unsigned short)(u >> 16);
}

static __device__ __forceinline__ unsigned pk2(float a, float b) {
    return (unsigned)f2bf(a) | ((unsigned)f2bf(b) << 16);
}

// ---------------------------------------------------------------------------
// Kernel 0: QKV projection. z = blockIdx.z selects (input, weight slice, dst).
//   out = X @ W_z^T + b_z ; q additionally scaled by 1/8.
//   z=0 -> Qp[bh][s][d], z=1 -> Kp[bh][s][d], z=2 -> Vt[bh][d][s] (transposed)
// 128x128 tile, BK=32, 4 waves (2x2 of 64x64), 16x16x32 bf16 MFMA.
// ---------------------------------------------------------------------------
__global__ __launch_bounds__(256) void qkv_kernel(
    const float* __restrict__ Xq, const float* __restrict__ Xk,
    const float* __restrict__ Xv, const float* __restrict__ W,
    const float* __restrict__ bias,
    unsigned short* __restrict__ Qp, unsigned short* __restrict__ Kp,
    unsigned short* __restrict__ Vt)
{
    __shared__ unsigned short lA[128][40];  // pad 32->40 shorts (80B rows)
    __shared__ unsigned short lB[128][40];

    const int z = blockIdx.z;
    const float* X  = (z == 0) ? Xq : (z == 1) ? Xk : Xv;
    const float* Wz = W + (size_t)z * 512 * 512;
    const int rb = blockIdx.y * 128;
    const int nb = blockIdx.x * 128;
    const int tid  = threadIdx.x;
    const int lane = tid & 63, wave = tid >> 6;
    const int wr = wave >> 1, wc = wave & 1;
    const int lq = lane & 15, lg = lane >> 4;

    f32x4 acc[4][4];
#pragma unroll
    for (int i = 0; i < 4; ++i)
#pragma unroll
        for (int j = 0; j < 4; ++j) acc[i][j] = (f32x4){0.f, 0.f, 0.f, 0.f};

    const int srow = tid >> 1;          // 0..127
    const int scol = (tid & 1) * 16;    // 0 or 16 (elements)

    for (int kt = 0; kt < 16; ++kt) {
        const int k0 = kt * 32;
        if (kt) __syncthreads();
        // stage A tile (fp32 -> bf16)
        {
            const float* g = X + (size_t)(rb + srow) * 512 + k0 + scol;
            float4 x0 = *(const float4*)(g + 0);
            float4 x1 = *(const float4*)(g + 4);
            float4 x2 = *(const float4*)(g + 8);
            float4 x3 = *(const float4*)(g + 12);
            uint4 w0, w1;
            w0.x = pk2(x0.x, x0.y); w0.y = pk2(x0.z, x0.w);
            w0.z = pk2(x1.x, x1.y); w0.w = pk2(x1.z, x1.w);
            w1.x = pk2(x2.x, x2.y); w1.y = pk2(x2.z, x2.w);
            w1.z = pk2(x3.x, x3.y); w1.w = pk2(x3.z, x3.w);
            *(uint4*)&lA[srow][scol] = w0;
            *(uint4*)&lA[srow][scol + 8] = w1;
        }
        // stage B tile (weights, fp32 -> bf16); W is [n][k], k contiguous
        {
            const float* g = Wz + (size_t)(nb + srow) * 512 + k0 + scol;
            float4 x0 = *(const float4*)(g + 0);
            float4 x1 = *(const float4*)(g + 4);
            float4 x2 = *(const float4*)(g + 8);
            float4 x3 = *(const float4*)(g + 12);
            uint4 w0, w1;
            w0.x = pk2(x0.x, x0.y); w0.y = pk2(x0.z, x0.w);
            w0.z = pk2(x1.x, x1.y); w0.w = pk2(x1.z, x1.w);
            w1.x = pk2(x2.x, x2.y); w1.y = pk2(x2.z, x2.w);
            w1.z = pk2(x3.x, x3.y); w1.w = pk2(x3.z, x3.w);
            *(uint4*)&lB[srow][scol] = w0;
            *(uint4*)&lB[srow][scol + 8] = w1;
        }
        __syncthreads();

        bf16x8 af[4], bf[4];
#pragma unroll
        for (int mi = 0; mi < 4; ++mi)
            af[mi] = *(const bf16x8*)&lA[wr * 64 + mi * 16 + lq][lg * 8];
#pragma unroll
        for (int ni = 0; ni < 4; ++ni)
            bf[ni] = *(const bf16x8*)&lB[wc * 64 + ni * 16 + lq][lg * 8];
#pragma unroll
        for (int mi = 0; mi < 4; ++mi)
#pragma unroll
            for (int ni = 0; ni < 4; ++ni)
                acc[mi][ni] = __builtin_amdgcn_mfma_f32_16x16x32_bf16(
                    af[mi], bf[ni], acc[mi][ni], 0, 0, 0);
    }

    // epilogue: C layout col = lane&15 (n), row = (lane>>4)*4 + r (m)
    const float* bz = bias + z * 512;
#pragma unroll
    for (int ni = 0; ni < 4; ++ni) {
        const int n = nb + wc * 64 + ni * 16 + lq;
        const float bv = bz[n];
        const int h = n >> 6, d = n & 63;
#pragma unroll
        for (int mi = 0; mi < 4; ++mi) {
#pragma unroll
            for (int r = 0; r < 4; ++r) {
                const int t = rb + wr * 64 + mi * 16 + lg * 4 + r;
                float v = acc[mi][ni][r] + bv;
                const int s = t >> 2, b = t & 3;
                if (z == 0) {
                    v *= 0.125f;  // 1/sqrt(D)
                    Qp[((size_t)(b * 8 + h) * 2048 + s) * 64 + d] = f2bf(v);
                } else if (z == 1) {
                    Kp[((size_t)(b * 8 + h) * 2048 + s) * 64 + d] = f2bf(v);
                } else {
                    Vt[((size_t)(b * 8 + h) * 64 + d) * 2048 + s] = f2bf(v);
                }
            }
        }
    }
}

// ---------------------------------------------------------------------------
// Kernel 1: flash attention. grid = (S/64 q-tiles, B*H). 4 waves, each owns
// 16 q rows. KV blocks of 64. Swapped QK^T: mfma(A=K, B=Q) -> S^T tile with
// col = q (lane&15), row = k. Online softmax per q-column via 4-group shfl.
// P -> per-wave padded LDS -> B-operand of PV mfma (A = V^T from Vt).
// ---------------------------------------------------------------------------
__global__ __launch_bounds__(256) void attn_kernel(
    const unsigned short* __restrict__ Qp, const unsigned short* __restrict__ Kp,
    const unsigned short* __restrict__ Vt, const float* __restrict__ mask,
    unsigned short* __restrict__ AO)
{
    __shared__ unsigned short lK[64][72];   // [k][d], pad 64->72
    __shared__ unsigned short lV[64][72];   // [d][k], pad 64->72
    __shared__ float          lM[64][68];   // [q][k], pad 64->68
    __shared__ unsigned short lP[4][16][72];// per-wave [q][k]

    const int bh = blockIdx.y;
    const int b = bh >> 3, h = bh & 7;
    const int qb = blockIdx.x * 64;
    const int tid  = threadIdx.x;
    const int lane = tid & 63, wave = tid >> 6;
    const int lq = lane & 15, lg = lane >> 4;

    const int qloc = wave * 16 + lq;
    const int qg = qb + qloc;
    const bf16x8 qf0 = *(const bf16x8*)(Qp + ((size_t)bh * 2048 + qg) * 64 + lg * 8);
    const bf16x8 qf1 = *(const bf16x8*)(Qp + ((size_t)bh * 2048 + qg) * 64 + 32 + lg * 8);

    f32x4 o[4];
#pragma unroll
    for (int di = 0; di < 4; ++di) o[di] = (f32x4){0.f, 0.f, 0.f, 0.f};
    float m = -3.0e38f, l = 0.f;

    const int srow = tid >> 2;          // 0..63
    const int sseg = (tid & 3) * 16;    // element offset

    for (int kb = 0; kb < 32; ++kb) {
        const int kv = kb * 64;
        if (kb) __syncthreads();
        {   // K tile [k][d]
            const unsigned short* g = Kp + ((size_t)bh * 2048 + kv + srow) * 64 + sseg;
            *(uint4*)&lK[srow][sseg]     = *(const uint4*)g;
            *(uint4*)&lK[srow][sseg + 8] = *(const uint4*)(g + 8);
        }
        {   // V^T tile [d][k]
            const unsigned short* g = Vt + ((size_t)bh * 64 + srow) * 2048 + kv + sseg;
            *(uint4*)&lV[srow][sseg]     = *(const uint4*)g;
            *(uint4*)&lV[srow][sseg + 8] = *(const uint4*)(g + 8);
        }
        {   // mask tile [q][k] fp32
            const float* g = mask + ((size_t)b * 2048 + qb + srow) * 2048 + kv + sseg;
            *(float4*)&lM[srow][sseg]      = *(const float4*)(g);
            *(float4*)&lM[srow][sseg + 4]  = *(const float4*)(g + 4);
            *(float4*)&lM[srow][sseg + 8]  = *(const float4*)(g + 8);
            *(float4*)&lM[srow][sseg + 12] = *(const float4*)(g + 12);
        }
        __syncthreads();

        // QK^T: 4 k-subtiles of 16, inner D=64 as 2 mfmas
        float zv[4][4];
#pragma unroll
        for (int sub = 0; sub < 4; ++sub) {
            bf16x8 a0 = *(const bf16x8*)&lK[sub * 16 + lq][lg * 8];
            bf16x8 a1 = *(const bf16x8*)&lK[sub * 16 + lq][32 + lg * 8];
            f32x4 sf = (f32x4){0.f, 0.f, 0.f, 0.f};
            sf = __builtin_amdgcn_mfma_f32_16x16x32_bf16(a0, qf0, sf, 0, 0, 0);
            sf = __builtin_amdgcn_mfma_f32_16x16x32_bf16(a1, qf1, sf, 0, 0, 0);
#pragma unroll
            for (int r = 0; r < 4; ++r)
                zv[sub][r] = sf[r] + lM[qloc][sub * 16 + lg * 4 + r];
        }

        // online softmax: row max over this lane's 16 + reduce across groups
        float mb = zv[0][0];
#pragma unroll
        for (int sub = 0; sub < 4; ++sub)
#pragma unroll
            for (int r = 0; r < 4; ++r) mb = fmaxf(mb, zv[sub][r]);
        mb = fmaxf(mb, __shfl_xor(mb, 16));
        mb = fmaxf(mb, __shfl_xor(mb, 32));
        const float mn = fmaxf(m, mb);
        const float al = exp2f((m - mn) * L2E);
        float ps = 0.f;
        unsigned pw[4][2];
#pragma unroll
        for (int sub = 0; sub < 4; ++sub) {
            float p0 = exp2f((zv[sub][0] - mn) * L2E);
            float p1 = exp2f((zv[sub][1] - mn) * L2E);
            float p2 = exp2f((zv[sub][2] - mn) * L2E);
            float p3 = exp2f((zv[sub][3] - mn) * L2E);
            ps += (p0 + p1) + (p2 + p3);
            pw[sub][0] = pk2(p0, p1);
            pw[sub][1] = pk2(p2, p3);
        }
        ps += __shfl_xor(ps, 16);
        ps += __shfl_xor(ps, 32);
        l = l * al + ps;
        m = mn;
#pragma unroll
        for (int di = 0; di < 4; ++di) {
            o[di][0] *= al; o[di][1] *= al; o[di][2] *= al; o[di][3] *= al;
        }
        // stash P (bf16) in per-wave LDS at [q][k]
#pragma unroll
        for (int sub = 0; sub < 4; ++sub) {
            unsigned* p = (unsigned*)&lP[wave][lq][sub * 16 + lg * 4];
            p[0] = pw[sub][0];
            p[1] = pw[sub][1];
        }
        // PV: O^T[d][q] += V^T x P^T  (2 k-slices of 32)
#pragma unroll
        for (int ks = 0; ks < 2; ++ks) {
            bf16x8 pb = *(const bf16x8*)&lP[wave][lq][ks * 32 + lg * 8];
#pragma unroll
            for (int di = 0; di < 4; ++di) {
                bf16x8 av = *(const bf16x8*)&lV[di * 16 + lq][ks * 32 + lg * 8];
                o[di] = __builtin_amdgcn_mfma_f32_16x16x32_bf16(av, pb, o[di], 0, 0, 0);
            }
        }
    }

    // epilogue: O^T layout col=q (lane&15), row=d -> AO[(s*B+b)*E + h*64+d]
    const float inv = 1.0f / l;
#pragma unroll
    for (int di = 0; di < 4; ++di)
#pragma unroll
        for (int r = 0; r < 4; ++r) {
            const int d = di * 16 + lg * 4 + r;
            AO[((size_t)qg * 4 + b) * 512 + h * 64 + d] = f2bf(o[di][r] * inv);
        }
}

// ---------------------------------------------------------------------------
// Kernel 2: output projection. out = AO(bf16) @ W_out^T + b_out (fp32 out).
// Same GEMM structure as qkv_kernel; A already bf16.
// ---------------------------------------------------------------------------
__global__ __launch_bounds__(256) void oproj_kernel(
    const unsigned short* __restrict__ A, const float* __restrict__ W,
    const float* __restrict__ bias, float* __restrict__ out)
{
    __shared__ unsigned short lA[128][40];
    __shared__ unsigned short lB[128][40];

    const int rb = blockIdx.y * 128;
    const int nb = blockIdx.x * 128;
    const int tid  = threadIdx.x;
    const int lane = tid & 63, wave = tid >> 6;
    const int wr = wave >> 1, wc = wave & 1;
    const int lq = lane & 15, lg = lane >> 4;

    f32x4 acc[4][4];
#pragma unroll
    for (int i = 0; i < 4; ++i)
#pragma unroll
        for (int j = 0; j < 4; ++j) acc[i][j] = (f32x4){0.f, 0.f, 0.f, 0.f};

    const int srow = tid >> 1;
    const int scol = (tid & 1) * 16;

    for (int kt = 0; kt < 16; ++kt) {
        const int k0 = kt * 32;
        if (kt) __syncthreads();
        {   // A tile (bf16 passthrough)
            const unsigned short* g = A + (size_t)(rb + srow) * 512 + k0 + scol;
            *(uint4*)&lA[srow][scol]     = *(const uint4*)g;
            *(uint4*)&lA[srow][scol + 8] = *(const uint4*)(g + 8);
        }
        {   // B tile (weights fp32 -> bf16)
            const float* g = W + (size_t)(nb + srow) * 512 + k0 + scol;
            float4 x0 = *(const float4*)(g + 0);
            float4 x1 = *(const float4*)(g + 4);
            float4 x2 = *(const float4*)(g + 8);
            float4 x3 = *(const float4*)(g + 12);
            uint4 w0, w1;
            w0.x = pk2(x0.x, x0.y); w0.y = pk2(x0.z, x0.w);
            w0.z = pk2(x1.x, x1.y); w0.w = pk2(x1.z, x1.w);
            w1.x = pk2(x2.x, x2.y); w1.y = pk2(x2.z, x2.w);
            w1.z = pk2(x3.x, x3.y); w1.w = pk2(x3.z, x3.w);
            *(uint4*)&lB[srow][scol] = w0;
            *(uint4*)&lB[srow][scol + 8] = w1;
        }
        __syncthreads();

        bf16x8 af[4], bfr[4];
#pragma unroll
        for (int mi = 0; mi < 4; ++mi)
            af[mi] = *(const bf16x8*)&lA[wr * 64 + mi * 16 + lq][lg * 8];
#pragma unroll
        for (int ni = 0; ni < 4; ++ni)
            bfr[ni] = *(const bf16x8*)&lB[wc * 64 + ni * 16 + lq][lg * 8];
#pragma unroll
        for (int mi = 0; mi < 4; ++mi)
#pragma unroll
            for (int ni = 0; ni < 4; ++ni)
                acc[mi][ni] = __builtin_amdgcn_mfma_f32_16x16x32_bf16(
                    af[mi], bfr[ni], acc[mi][ni], 0, 0, 0);
    }

#pragma unroll
    for (int ni = 0; ni < 4; ++ni) {
        const int n = nb + wc * 64 + ni * 16 + lq;
        const float bv = bias[n];
#pragma unroll
        for (int mi = 0; mi < 4; ++mi) {
#pragma unroll
            for (int r = 0; r < 4; ++r) {
                const int t = rb + wr * 64 + mi * 16 + lg * 4 + r;
                out[(size_t)t * 512 + n] = acc[mi][ni][r] + bv;
            }
        }
    }
}

extern "C" void kernel_launch(void* const* d_in, const int* in_sizes, int n_in,
                              void* d_out, int out_size, void* d_ws, size_t ws_size,
                              hipStream_t stream)
{
    (void)in_sizes; (void)n_in; (void)out_size; (void)ws_size;
    const float* query = (const float*)d_in[0];
    const float* key   = (const float*)d_in[1];
    const float* value = (const float*)d_in[2];
    const float* mask  = (const float*)d_in[3];
    const float* w_in  = (const float*)d_in[4];
    const float* b_in  = (const float*)d_in[5];
    const float* w_out = (const float*)d_in[6];
    const float* b_out = (const float*)d_in[7];
    float* out = (float*)d_out;

    char* ws = (char*)d_ws;
    unsigned short* Qp = (unsigned short*)(ws);                       // [32][2048][64] bf16
    unsigned short* Kp = (unsigned short*)(ws + (size_t)8 * 1024 * 1024);
    unsigned short* Vt = (unsigned short*)(ws + (size_t)16 * 1024 * 1024); // [32][64][2048]
    unsigned short* AO = (unsigned short*)(ws + (size_t)24 * 1024 * 1024); // [8192][512]

    qkv_kernel<<<dim3(4, 64, 3), 256, 0, stream>>>(query, key, value, w_in, b_in,
                                                   Qp, Kp, Vt);
    attn_kernel<<<dim3(32, 32), 256, 0, stream>>>(Qp, Kp, Vt, mask, AO);
    oproj_kernel<<<dim3(4, 64), 256, 0, stream>>>(AO, w_out, b_out, out);
}

// Round 2
// 156.741 us; speedup vs baseline: 1.2252x; 1.2252x over previous
//
#include <hip/hip_runtime.h>

// MHA forward: S=2048, B=4, E=512, H=8, D=64.
// Pipeline: qkv_kernel (3x GEMM 8192x512x512, bf16 MFMA) -> attn_kernel
// (flash attention, 64-q-row tiles, KV blocks of 64) -> oproj_kernel (GEMM).
// R2: v_cvt_pk_bf16_f32 packing, mask as MFMA acc-init direct from global
// (lM LDS tile removed), defer-max rescale skip (THR=8).

#define L2E 1.44269504088896340736f

typedef __attribute__((ext_vector_type(8))) __bf16 bf16x8;
typedef __attribute__((ext_vector_type(4))) float f32x4;

static __device__ __forceinline__ unsigned short f2bf(float f) {
    union { float f; unsigned u; } v; v.f = f;
    unsigned u = v.u + 0x7fffu + ((v.u >> 16) & 1u);
    return (unsigned short)(u >> 16);
}

// packed bf16 pair: lo = cvt(a), hi = cvt(b)  (hardware RNE converter)
static __device__ __forceinline__ unsigned cvtpk(float a, float b) {
    unsigned r;
    asm("v_cvt_pk_bf16_f32 %0, %1, %2" : "=v"(r) : "v"(a), "v"(b));
    return r;
}

// ---------------------------------------------------------------------------
// Kernel 0: QKV projection. z = blockIdx.z selects (input, weight slice, dst).
//   out = X @ W_z^T + b_z ; q additionally scaled by 1/8.
//   z=0 -> Qp[bh][s][d], z=1 -> Kp[bh][s][d], z=2 -> Vt[bh][d][s] (transposed)
// 128x128 tile, BK=32, 4 waves (2x2 of 64x64), 16x16x32 bf16 MFMA.
// ---------------------------------------------------------------------------
__global__ __launch_bounds__(256) void qkv_kernel(
    const float* __restrict__ Xq, const float* __restrict__ Xk,
    const float* __restrict__ Xv, const float* __restrict__ W,
    const float* __restrict__ bias,
    unsigned short* __restrict__ Qp, unsigned short* __restrict__ Kp,
    unsigned short* __restrict__ Vt)
{
    __shared__ unsigned short lA[128][40];  // pad 32->40 shorts (80B rows)
    __shared__ unsigned short lB[128][40];

    const int z = blockIdx.z;
    const float* X  = (z == 0) ? Xq : (z == 1) ? Xk : Xv;
    const float* Wz = W + (size_t)z * 512 * 512;
    const int rb = blockIdx.y * 128;
    const int nb = blockIdx.x * 128;
    const int tid  = threadIdx.x;
    const int lane = tid & 63, wave = tid >> 6;
    const int wr = wave >> 1, wc = wave & 1;
    const int lq = lane & 15, lg = lane >> 4;

    f32x4 acc[4][4];
#pragma unroll
    for (int i = 0; i < 4; ++i)
#pragma unroll
        for (int j = 0; j < 4; ++j) acc[i][j] = (f32x4){0.f, 0.f, 0.f, 0.f};

    const int srow = tid >> 1;          // 0..127
    const int scol = (tid & 1) * 16;    // 0 or 16 (elements)

    for (int kt = 0; kt < 16; ++kt) {
        const int k0 = kt * 32;
        if (kt) __syncthreads();
        // stage A tile (fp32 -> bf16)
        {
            const float* g = X + (size_t)(rb + srow) * 512 + k0 + scol;
            float4 x0 = *(const float4*)(g + 0);
            float4 x1 = *(const float4*)(g + 4);
            float4 x2 = *(const float4*)(g + 8);
            float4 x3 = *(const float4*)(g + 12);
            uint4 w0, w1;
            w0.x = cvtpk(x0.x, x0.y); w0.y = cvtpk(x0.z, x0.w);
            w0.z = cvtpk(x1.x, x1.y); w0.w = cvtpk(x1.z, x1.w);
            w1.x = cvtpk(x2.x, x2.y); w1.y = cvtpk(x2.z, x2.w);
            w1.z = cvtpk(x3.x, x3.y); w1.w = cvtpk(x3.z, x3.w);
            *(uint4*)&lA[srow][scol] = w0;
            *(uint4*)&lA[srow][scol + 8] = w1;
        }
        // stage B tile (weights, fp32 -> bf16); W is [n][k], k contiguous
        {
            const float* g = Wz + (size_t)(nb + srow) * 512 + k0 + scol;
            float4 x0 = *(const float4*)(g + 0);
            float4 x1 = *(const float4*)(g + 4);
            float4 x2 = *(const float4*)(g + 8);
            float4 x3 = *(const float4*)(g + 12);
            uint4 w0, w1;
            w0.x = cvtpk(x0.x, x0.y); w0.y = cvtpk(x0.z, x0.w);
            w0.z = cvtpk(x1.x, x1.y); w0.w = cvtpk(x1.z, x1.w);
            w1.x = cvtpk(x2.x, x2.y); w1.y = cvtpk(x2.z, x2.w);
            w1.z = cvtpk(x3.x, x3.y); w1.w = cvtpk(x3.z, x3.w);
            *(uint4*)&lB[srow][scol] = w0;
            *(uint4*)&lB[srow][scol + 8] = w1;
        }
        __syncthreads();

        bf16x8 af[4], bf[4];
#pragma unroll
        for (int mi = 0; mi < 4; ++mi)
            af[mi] = *(const bf16x8*)&lA[wr * 64 + mi * 16 + lq][lg * 8];
#pragma unroll
        for (int ni = 0; ni < 4; ++ni)
            bf[ni] = *(const bf16x8*)&lB[wc * 64 + ni * 16 + lq][lg * 8];
#pragma unroll
        for (int mi = 0; mi < 4; ++mi)
#pragma unroll
            for (int ni = 0; ni < 4; ++ni)
                acc[mi][ni] = __builtin_amdgcn_mfma_f32_16x16x32_bf16(
                    af[mi], bf[ni], acc[mi][ni], 0, 0, 0);
    }

    // epilogue: C layout col = lane&15 (n), row = (lane>>4)*4 + r (m)
    const float* bz = bias + z * 512;
#pragma unroll
    for (int ni = 0; ni < 4; ++ni) {
        const int n = nb + wc * 64 + ni * 16 + lq;
        const float bv = bz[n];
        const int h = n >> 6, d = n & 63;
#pragma unroll
        for (int mi = 0; mi < 4; ++mi) {
#pragma unroll
            for (int r = 0; r < 4; ++r) {
                const int t = rb + wr * 64 + mi * 16 + lg * 4 + r;
                float v = acc[mi][ni][r] + bv;
                const int s = t >> 2, b = t & 3;
                if (z == 0) {
                    v *= 0.125f;  // 1/sqrt(D)
                    Qp[((size_t)(b * 8 + h) * 2048 + s) * 64 + d] = f2bf(v);
                } else if (z == 1) {
                    Kp[((size_t)(b * 8 + h) * 2048 + s) * 64 + d] = f2bf(v);
                } else {
                    Vt[((size_t)(b * 8 + h) * 64 + d) * 2048 + s] = f2bf(v);
                }
            }
        }
    }
}

// ---------------------------------------------------------------------------
// Kernel 1: flash attention. grid = (S/64 q-tiles, B*H). 4 waves, each owns
// 16 q rows. KV blocks of 64. Swapped QK^T: mfma(A=K, B=Q) -> S^T tile with
// col = q (lane&15), row = k. Mask enters as the MFMA accumulator init,
// loaded per-lane straight from global (float4 matches fragment layout).
// Online softmax per q-column via shfl_xor 16/32; defer-max THR=8.
// ---------------------------------------------------------------------------
__global__ __launch_bounds__(256) void attn_kernel(
    const unsigned short* __restrict__ Qp, const unsigned short* __restrict__ Kp,
    const unsigned short* __restrict__ Vt, const float* __restrict__ mask,
    unsigned short* __restrict__ AO)
{
    __shared__ unsigned short lK[64][72];   // [k][d], pad 64->72
    __shared__ unsigned short lV[64][72];   // [d][k], pad 64->72
    __shared__ unsigned short lP[4][16][72];// per-wave [q][k]

    const int bh = blockIdx.y;
    const int b = bh >> 3, h = bh & 7;
    const int qb = blockIdx.x * 64;
    const int tid  = threadIdx.x;
    const int lane = tid & 63, wave = tid >> 6;
    const int lq = lane & 15, lg = lane >> 4;

    const int qloc = wave * 16 + lq;
    const int qg = qb + qloc;
    const unsigned short* Kbase = Kp + (size_t)bh * 2048 * 64;
    const unsigned short* Vbase = Vt + (size_t)bh * 64 * 2048;
    const float* mrow = mask + ((size_t)b * 2048 + qg) * 2048 + lg * 4;

    const bf16x8 qf0 = *(const bf16x8*)(Qp + ((size_t)bh * 2048 + qg) * 64 + lg * 8);
    const bf16x8 qf1 = *(const bf16x8*)(Qp + ((size_t)bh * 2048 + qg) * 64 + 32 + lg * 8);

    f32x4 o[4];
#pragma unroll
    for (int di = 0; di < 4; ++di) o[di] = (f32x4){0.f, 0.f, 0.f, 0.f};
    float m = -3.0e38f, l = 0.f;

    const int srow = tid >> 2;          // 0..63
    const int sseg = (tid & 3) * 16;    // element offset

    for (int kb = 0; kb < 32; ++kb) {
        const int kv = kb * 64;
        if (kb) __syncthreads();
        {   // K tile [k][d]
            const unsigned short* g = Kbase + (size_t)(kv + srow) * 64 + sseg;
            *(uint4*)&lK[srow][sseg]     = *(const uint4*)g;
            *(uint4*)&lK[srow][sseg + 8] = *(const uint4*)(g + 8);
        }
        {   // V^T tile [d][k]
            const unsigned short* g = Vbase + (size_t)srow * 2048 + kv + sseg;
            *(uint4*)&lV[srow][sseg]     = *(const uint4*)g;
            *(uint4*)&lV[srow][sseg + 8] = *(const uint4*)(g + 8);
        }
        // mask prefetch (acc-init layout: k = sub*16+lg*4+r, q = lq)
        float4 mv[4];
#pragma unroll
        for (int sub = 0; sub < 4; ++sub)
            mv[sub] = *(const float4*)(mrow + kv + sub * 16);
        __syncthreads();

        // QK^T: acc starts at mask, 2 mfmas cover D=64
        f32x4 zv[4];
#pragma unroll
        for (int sub = 0; sub < 4; ++sub) {
            bf16x8 a0 = *(const bf16x8*)&lK[sub * 16 + lq][lg * 8];
            bf16x8 a1 = *(const bf16x8*)&lK[sub * 16 + lq][32 + lg * 8];
            f32x4 sf = (f32x4){mv[sub].x, mv[sub].y, mv[sub].z, mv[sub].w};
            sf = __builtin_amdgcn_mfma_f32_16x16x32_bf16(a0, qf0, sf, 0, 0, 0);
            sf = __builtin_amdgcn_mfma_f32_16x16x32_bf16(a1, qf1, sf, 0, 0, 0);
            zv[sub] = sf;
        }

        // online softmax (per q-column = per lq across lg groups)
        float mb = zv[0][0];
#pragma unroll
        for (int sub = 0; sub < 4; ++sub)
#pragma unroll
            for (int r = 0; r < 4; ++r) mb = fmaxf(mb, zv[sub][r]);
        mb = fmaxf(mb, __shfl_xor(mb, 16));
        mb = fmaxf(mb, __shfl_xor(mb, 32));

        if (!__all(mb <= m + 8.0f)) {   // defer-max: skip rescale when bounded
            const float mn = fmaxf(m, mb);
            const float al = exp2f((m - mn) * L2E);
#pragma unroll
            for (int di = 0; di < 4; ++di) {
                o[di][0] *= al; o[di][1] *= al; o[di][2] *= al; o[di][3] *= al;
            }
            l *= al;
            m = mn;
        }

        float ps = 0.f;
        unsigned pw[4][2];
#pragma unroll
        for (int sub = 0; sub < 4; ++sub) {
            float p0 = exp2f((zv[sub][0] - m) * L2E);
            float p1 = exp2f((zv[sub][1] - m) * L2E);
            float p2 = exp2f((zv[sub][2] - m) * L2E);
            float p3 = exp2f((zv[sub][3] - m) * L2E);
            ps += (p0 + p1) + (p2 + p3);
            pw[sub][0] = cvtpk(p0, p1);
            pw[sub][1] = cvtpk(p2, p3);
        }
        ps += __shfl_xor(ps, 16);
        ps += __shfl_xor(ps, 32);
        l += ps;

        // stash P (bf16) in per-wave LDS at [q][k]
#pragma unroll
        for (int sub = 0; sub < 4; ++sub)
            *(uint2*)&lP[wave][lq][sub * 16 + lg * 4] = make_uint2(pw[sub][0], pw[sub][1]);

        // PV: O^T[d][q] += V^T x P^T  (2 k-slices of 32)
#pragma unroll
        for (int ks = 0; ks < 2; ++ks) {
            bf16x8 pb = *(const bf16x8*)&lP[wave][lq][ks * 32 + lg * 8];
#pragma unroll
            for (int di = 0; di < 4; ++di) {
                bf16x8 av = *(const bf16x8*)&lV[di * 16 + lq][ks * 32 + lg * 8];
                o[di] = __builtin_amdgcn_mfma_f32_16x16x32_bf16(av, pb, o[di], 0, 0, 0);
            }
        }
    }

    // epilogue: O^T layout col=q (lane&15), row=d -> AO[(s*B+b)*E + h*64+d]
    const float inv = 1.0f / l;
    unsigned short* aobase = AO + ((size_t)qg * 4 + b) * 512 + h * 64;
#pragma unroll
    for (int di = 0; di < 4; ++di) {
        const int d = di * 16 + lg * 4;
        unsigned u0 = cvtpk(o[di][0] * inv, o[di][1] * inv);
        unsigned u1 = cvtpk(o[di][2] * inv, o[di][3] * inv);
        *(uint2*)(aobase + d) = make_uint2(u0, u1);
    }
}

// ---------------------------------------------------------------------------
// Kernel 2: output projection. out = AO(bf16) @ W_out^T + b_out (fp32 out).
// ---------------------------------------------------------------------------
__global__ __launch_bounds__(256) void oproj_kernel(
    const unsigned short* __restrict__ A, const float* __restrict__ W,
    const float* __restrict__ bias, float* __restrict__ out)
{
    __shared__ unsigned short lA[128][40];
    __shared__ unsigned short lB[128][40];

    const int rb = blockIdx.y * 128;
    const int nb = blockIdx.x * 128;
    const int tid  = threadIdx.x;
    const int lane = tid & 63, wave = tid >> 6;
    const int wr = wave >> 1, wc = wave & 1;
    const int lq = lane & 15, lg = lane >> 4;

    f32x4 acc[4][4];
#pragma unroll
    for (int i = 0; i < 4; ++i)
#pragma unroll
        for (int j = 0; j < 4; ++j) acc[i][j] = (f32x4){0.f, 0.f, 0.f, 0.f};

    const int srow = tid >> 1;
    const int scol = (tid & 1) * 16;

    for (int kt = 0; kt < 16; ++kt) {
        const int k0 = kt * 32;
        if (kt) __syncthreads();
        {   // A tile (bf16 passthrough)
            const unsigned short* g = A + (size_t)(rb + srow) * 512 + k0 + scol;
            *(uint4*)&lA[srow][scol]     = *(const uint4*)g;
            *(uint4*)&lA[srow][scol + 8] = *(const uint4*)(g + 8);
        }
        {   // B tile (weights fp32 -> bf16)
            const float* g = W + (size_t)(nb + srow) * 512 + k0 + scol;
            float4 x0 = *(const float4*)(g + 0);
            float4 x1 = *(const float4*)(g + 4);
            float4 x2 = *(const float4*)(g + 8);
            float4 x3 = *(const float4*)(g + 12);
            uint4 w0, w1;
            w0.x = cvtpk(x0.x, x0.y); w0.y = cvtpk(x0.z, x0.w);
            w0.z = cvtpk(x1.x, x1.y); w0.w = cvtpk(x1.z, x1.w);
            w1.x = cvtpk(x2.x, x2.y); w1.y = cvtpk(x2.z, x2.w);
            w1.z = cvtpk(x3.x, x3.y); w1.w = cvtpk(x3.z, x3.w);
            *(uint4*)&lB[srow][scol] = w0;
            *(uint4*)&lB[srow][scol + 8] = w1;
        }
        __syncthreads();

        bf16x8 af[4], bfr[4];
#pragma unroll
        for (int mi = 0; mi < 4; ++mi)
            af[mi] = *(const bf16x8*)&lA[wr * 64 + mi * 16 + lq][lg * 8];
#pragma unroll
        for (int ni = 0; ni < 4; ++ni)
            bfr[ni] = *(const bf16x8*)&lB[wc * 64 + ni * 16 + lq][lg * 8];
#pragma unroll
        for (int mi = 0; mi < 4; ++mi)
#pragma unroll
            for (int ni = 0; ni < 4; ++ni)
                acc[mi][ni] = __builtin_amdgcn_mfma_f32_16x16x32_bf16(
                    af[mi], bfr[ni], acc[mi][ni], 0, 0, 0);
    }

#pragma unroll
    for (int ni = 0; ni < 4; ++ni) {
        const int n = nb + wc * 64 + ni * 16 + lq;
        const float bv = bias[n];
#pragma unroll
        for (int mi = 0; mi < 4; ++mi) {
#pragma unroll
            for (int r = 0; r < 4; ++r) {
                const int t = rb + wr * 64 + mi * 16 + lg * 4 + r;
                out[(size_t)t * 512 + n] = acc[mi][ni][r] + bv;
            }
        }
    }
}

extern "C" void kernel_launch(void* const* d_in, const int* in_sizes, int n_in,
                              void* d_out, int out_size, void* d_ws, size_t ws_size,
                              hipStream_t stream)
{
    (void)in_sizes; (void)n_in; (void)out_size; (void)ws_size;
    const float* query = (const float*)d_in[0];
    const float* key   = (const float*)d_in[1];
    const float* value = (const float*)d_in[2];
    const float* mask  = (const float*)d_in[3];
    const float* w_in  = (const float*)d_in[4];
    const float* b_in  = (const float*)d_in[5];
    const float* w_out = (const float*)d_in[6];
    const float* b_out = (const float*)d_in[7];
    float* out = (float*)d_out;

    char* ws = (char*)d_ws;
    unsigned short* Qp = (unsigned short*)(ws);                       // [32][2048][64] bf16
    unsigned short* Kp = (unsigned short*)(ws + (size_t)8 * 1024 * 1024);
    unsigned short* Vt = (unsigned short*)(ws + (size_t)16 * 1024 * 1024); // [32][64][2048]
    unsigned short* AO = (unsigned short*)(ws + (size_t)24 * 1024 * 1024); // [8192][512]

    qkv_kernel<<<dim3(4, 64, 3), 256, 0, stream>>>(query, key, value, w_in, b_in,
                                                   Qp, Kp, Vt);
    attn_kernel<<<dim3(32, 32), 256, 0, stream>>>(Qp, Kp, Vt, mask, AO);
    oproj_kernel<<<dim3(4, 64), 256, 0, stream>>>(AO, w_out, b_out, out);
}